// Round 2
// baseline (8385.905 us; speedup 1.0000x reference)
//
#include <hip/hip_runtime.h>

// Problem shape (fixed by setup_inputs): B=4, N=16384, NPOINT=1024, nsample=1,
// radius=0.5. xyz input layout is [B,3,N]. Output: int32 [B,NPOINT,1].
//
// FPS: one block per batch (the 1023-step loop is serial; cross-block sync
// would cost more than an iteration). 512 threads = 8 waves = 2 waves/SIMD,
// 32 points/thread in registers (px/py/pz/dst = 128 VGPRs of state).
// amdgpu_waves_per_eu(2,2) pins the allocator budget at 256 VGPRs so the
// state stays in architectural VGPRs (without it the allocator squeezed to
// 96 VGPRs and paid per-access AGPR moves — the hidden 2x issue inflation
// seen in rounds 0/1).
//
// Per iteration (ONE barrier):
//   pk-math distance update -> depth-5 tree argmax in-thread (left-wins-ties
//   == numpy first-occurrence; leaf ids are inline consts 0..31) -> packed
//   (value<<32 | 16383-idx) key -> 6-level wave butterfly -> lane0 writes LDS
//   (double-buffered) -> barrier -> all threads tree-max the 8 wave keys.
// Distance math replicates numpy exactly: ((dx*dx+dy*dy)+dz*dz), every op RN:
// fp contract(off) prevents fma fusion; v_pk_add/mul_f32 are per-half RN.

constexpr int N_PTS  = 16384;
constexpr int NPOINT = 1024;
constexpr int BLOCK  = 512;            // 8 waves -> 2 waves/SIMD
constexpr int KPT    = N_PTS / BLOCK;  // 32 points/thread
constexpr int KP2    = KPT / 2;        // 16 register pairs
constexpr int NWAVE  = BLOCK / 64;     // 8

typedef float f32x2 __attribute__((ext_vector_type(2)));

// Packed argmax key: distances (and x-coords) are >= 0, so IEEE bit pattern
// order == float order. High 32 bits = value bits, low bits = (N-1-idx) so
// u64 max gives (max value, tie -> min index) == np.argmax semantics.
__device__ inline unsigned long long pack_key(float v, int idx) {
    return ((unsigned long long)__float_as_uint(v) << 32) |
           (unsigned)(N_PTS - 1 - idx);
}
__device__ inline int key_idx(unsigned long long k) {
    return N_PTS - 1 - (int)(k & 0xFFFFu);
}
__device__ inline unsigned long long umax64(unsigned long long a,
                                            unsigned long long b) {
    return a > b ? a : b;
}

__global__ __attribute__((amdgpu_waves_per_eu(2, 2)))
__launch_bounds__(BLOCK) void fps_kernel(
    const float* __restrict__ xyz,   // [B,3,N]
    int* __restrict__ cent)          // [B,NPOINT] workspace
{
#pragma clang fp contract(off)
    const int b   = blockIdx.x;
    const int tid = threadIdx.x;
    const float* X = xyz + (size_t)b * 3 * N_PTS;
    const float* Y = X + N_PTS;
    const float* Z = X + 2 * N_PTS;

    f32x2 px[KP2], py[KP2], pz[KP2], dd[KP2];
#pragma unroll
    for (int k = 0; k < KP2; ++k) {
        const int p0 = tid + (2 * k) * BLOCK;      // coalesced per component
        const int p1 = tid + (2 * k + 1) * BLOCK;
        px[k] = f32x2{X[p0], X[p1]};
        py[k] = f32x2{Y[p0], Y[p1]};
        pz[k] = f32x2{Z[p0], Z[p1]};
        dd[k] = f32x2{1e10f, 1e10f};               // BIG
    }

    __shared__ unsigned long long s_key[2][NWAVE];  // double-buffered

    const int wave = tid >> 6;
    const int lane = tid & 63;

    // ---- initial far: argmax over x (first occurrence) via tree ----
    int far;
    {
        float v[KPT]; int kk[KPT];
#pragma unroll
        for (int k = 0; k < KP2; ++k) {
            v[2 * k]     = px[k].x;  kk[2 * k]     = 2 * k;
            v[2 * k + 1] = px[k].y;  kk[2 * k + 1] = 2 * k + 1;
        }
#pragma unroll
        for (int s = 1; s < KPT; s <<= 1) {
#pragma unroll
            for (int j = 0; j < KPT; j += 2 * s) {
                const bool ge = v[j] >= v[j + s];   // left wins ties -> min idx
                v[j]  = ge ? v[j]  : v[j + s];
                kk[j] = ge ? kk[j] : kk[j + s];
            }
        }
        unsigned long long key = pack_key(v[0], tid + kk[0] * BLOCK);
#pragma unroll
        for (int off = 32; off > 0; off >>= 1)
            key = umax64(key, __shfl_xor(key, off));
        if (lane == 0) s_key[0][wave] = key;
        __syncthreads();
        const unsigned long long* sk = s_key[0];
        const unsigned long long bk =
            umax64(umax64(umax64(sk[0], sk[1]), umax64(sk[2], sk[3])),
                   umax64(umax64(sk[4], sk[5]), umax64(sk[6], sk[7])));
        far = __builtin_amdgcn_readfirstlane(key_idx(bk));
    }

    // ---- main FPS loop: one barrier per iteration ----
    for (int it = 0; it < NPOINT; ++it) {
        if (tid == 0) cent[b * NPOINT + it] = far;   // record PRE-update far
        if (it == NPOINT - 1) break;                 // last update is unused

        // centroid coords: far is uniform (SGPR) -> scalar broadcast loads
        const float cx = X[far];
        const float cy = Y[far];
        const float cz = Z[far];
        const f32x2 c2x = {cx, cx};
        const f32x2 c2y = {cy, cy};
        const f32x2 c2z = {cz, cz};

#pragma unroll
        for (int k = 0; k < KP2; ++k) {
            const f32x2 dx = px[k] - c2x;            // v_pk_add_f32 (neg), RN
            const f32x2 dy = py[k] - c2y;
            const f32x2 dz = pz[k] - c2z;
            const f32x2 d  = (dx * dx + dy * dy) + dz * dz;  // RN, no fma
            dd[k].x = fminf(dd[k].x, d.x);
            dd[k].y = fminf(dd[k].y, d.y);
        }

        // in-thread argmax: depth-5 tree, left-wins-ties == first occurrence
        float v[KPT]; int kk[KPT];
#pragma unroll
        for (int k = 0; k < KP2; ++k) {
            v[2 * k]     = dd[k].x;  kk[2 * k]     = 2 * k;
            v[2 * k + 1] = dd[k].y;  kk[2 * k + 1] = 2 * k + 1;
        }
#pragma unroll
        for (int s = 1; s < KPT; s <<= 1) {
#pragma unroll
            for (int j = 0; j < KPT; j += 2 * s) {
                const bool ge = v[j] >= v[j + s];
                v[j]  = ge ? v[j]  : v[j + s];
                kk[j] = ge ? kk[j] : kk[j + s];
            }
        }

        unsigned long long key = pack_key(v[0], tid + kk[0] * BLOCK);
#pragma unroll
        for (int off = 32; off > 0; off >>= 1)
            key = umax64(key, __shfl_xor(key, off));
        const int buf = (it + 1) & 1;
        if (lane == 0) s_key[buf][wave] = key;
        __syncthreads();

        const unsigned long long* sk = s_key[buf];
        const unsigned long long bk =
            umax64(umax64(umax64(sk[0], sk[1]), umax64(sk[2], sk[3])),
                   umax64(umax64(sk[4], sk[5]), umax64(sk[6], sk[7])));
        far = __builtin_amdgcn_readfirstlane(key_idx(bk));
    }
}

// ---------------------------------------------------------------------------
// Ball query, nsample=1: one wave per centroid; scan 64-point chunks from
// index 0, first hit wins (== min index within radius). Distance replicated
// as the reference einsum: ((-2*dot) + |c|^2) + |p|^2; keep-test d <= 0.25.
// ---------------------------------------------------------------------------
__global__ __launch_bounds__(256) void ballq_kernel(
    const float* __restrict__ xyz,   // [B,3,N]
    const int* __restrict__ cent,    // [B,NPOINT]
    int* __restrict__ out)           // [B,NPOINT]
{
    const int gw   = (blockIdx.x * 256 + threadIdx.x) >> 6; // global wave id
    const int lane = threadIdx.x & 63;
    const int b = gw / NPOINT;
    const int s = gw % NPOINT;

    const float* X = xyz + (size_t)b * 3 * N_PTS;
    const float* Y = X + N_PTS;
    const float* Z = X + 2 * N_PTS;

    const int ci = cent[b * NPOINT + s];
    const float cx = X[ci];
    const float cy = Y[ci];
    const float cz = Z[ci];
    const float cn = __fadd_rn(
        __fadd_rn(__fmul_rn(cx, cx), __fmul_rn(cy, cy)), __fmul_rn(cz, cz));

    int res = N_PTS;
    for (int base = 0; base < N_PTS; base += 64) {
        const int p = base + lane;
        const float x = X[p];
        const float y = Y[p];
        const float z = Z[p];
        const float dot = __fadd_rn(
            __fadd_rn(__fmul_rn(x, cx), __fmul_rn(y, cy)), __fmul_rn(z, cz));
        const float pn = __fadd_rn(
            __fadd_rn(__fmul_rn(x, x), __fmul_rn(y, y)), __fmul_rn(z, z));
        const float d = __fadd_rn(__fadd_rn(__fmul_rn(-2.0f, dot), cn), pn);
        const bool hit = !(d > 0.25f);
        const unsigned long long m = __ballot(hit);
        if (m) {                       // wave-uniform branch
            res = base + (__ffsll((long long)m) - 1);
            break;
        }
    }
    if (lane == 0) out[b * NPOINT + s] = res;
}

extern "C" void kernel_launch(void* const* d_in, const int* in_sizes, int n_in,
                              void* d_out, int out_size, void* d_ws, size_t ws_size,
                              hipStream_t stream) {
    const float* xyz = (const float*)d_in[0];
    const int B = in_sizes[1] / 16;          // cls_label is [B,16]
    int* cent = (int*)d_ws;                  // [B, NPOINT] scratch
    int* out  = (int*)d_out;                 // int32 [B, NPOINT, 1]

    fps_kernel<<<B, BLOCK, 0, stream>>>(xyz, cent);

    const int nwaves  = B * NPOINT;          // one wave per centroid
    const int nblocks = nwaves / 4;          // 256 threads = 4 waves/block
    ballq_kernel<<<nblocks, 256, 0, stream>>>(xyz, cent, out);
}

// Round 3
// 1898.893 us; speedup vs baseline: 4.4162x; 4.4162x over previous
//
#include <hip/hip_runtime.h>

// Problem shape (fixed by setup_inputs): B=4, N=16384, NPOINT=1024, nsample=1,
// radius=0.5. xyz input layout is [B,3,N]. Output: int32 [B,NPOINT,1].
//
// FPS: one block per batch (serial 1023-step loop; cross-block sync costs more
// than an iteration). 512 threads = 8 waves = 2 waves/SIMD, 32 points/thread.
//
// KEY FIX vs rounds 0-2: the point cloud (px/py/pz, 96 floats/thread) is
// pinned in VGPRs with an opaque asm identity after the initial load. Without
// it the register allocator REMATERIALIZES the global loads every iteration
// (VGPR_Count 96 << 128 floats of state, flat FETCH because L2 absorbs the
// 196 KB/block/iter re-read) — that remat traffic, not VALU math, dominated
// rounds 0-2. LLVM cannot remat through inline asm, so the values stay live;
// __launch_bounds__(512,2) gives the 256-VGPR budget they need.
//
// Per iteration (ONE barrier):
//   pk-math distance update + fused min/argmax tracking (strict '>' with
//   ascending k == numpy first-occurrence; cndmask sources are inline consts
//   0..31) -> packed (value<<32 | 16383-idx) key -> 6-level wave butterfly ->
//   lane0 writes LDS (double-buffered) -> barrier -> tree-max of 8 wave keys.
// Distance math replicates numpy exactly: ((dx*dx+dy*dy)+dz*dz), every op RN:
// v_pk_add/v_pk_mul are per-half RN; subtraction = add of exact negation.

constexpr int N_PTS  = 16384;
constexpr int NPOINT = 1024;
constexpr int BLOCK  = 512;            // 8 waves -> 2 waves/SIMD
constexpr int KPT    = N_PTS / BLOCK;  // 32 points/thread
constexpr int KP2    = KPT / 2;        // 16 register pairs per component
constexpr int NWAVE  = BLOCK / 64;     // 8

typedef float f32x2 __attribute__((ext_vector_type(2)));

__device__ inline f32x2 pk_add(f32x2 a, f32x2 b) {
    f32x2 d;
    asm("v_pk_add_f32 %0, %1, %2" : "=v"(d) : "v"(a), "v"(b));
    return d;
}
__device__ inline f32x2 pk_mul(f32x2 a, f32x2 b) {
    f32x2 d;
    asm("v_pk_mul_f32 %0, %1, %2" : "=v"(d) : "v"(a), "v"(b));
    return d;
}

// Packed argmax key: distances (and x-coords) are >= 0, so IEEE bit pattern
// order == float order. High 32 bits = value bits, low bits = (N-1-idx) so
// u64 max gives (max value, tie -> min index) == np.argmax semantics.
__device__ inline unsigned long long pack_key(float v, int idx) {
    return ((unsigned long long)__float_as_uint(v) << 32) |
           (unsigned)(N_PTS - 1 - idx);
}
__device__ inline int key_idx(unsigned long long k) {
    return N_PTS - 1 - (int)(k & 0xFFFFu);
}
__device__ inline unsigned long long umax64(unsigned long long a,
                                            unsigned long long b) {
    return a > b ? a : b;
}

__global__ __launch_bounds__(BLOCK, 2) void fps_kernel(
    const float* __restrict__ xyz,   // [B,3,N]
    int* __restrict__ cent)          // [B,NPOINT] workspace
{
    const int b   = blockIdx.x;
    const int tid = threadIdx.x;
    const float* X = xyz + (size_t)b * 3 * N_PTS;
    const float* Y = X + N_PTS;
    const float* Z = X + 2 * N_PTS;

    f32x2 px[KP2], py[KP2], pz[KP2], dd[KP2];
#pragma unroll
    for (int k = 0; k < KP2; ++k) {
        const int p0 = tid + (2 * k) * BLOCK;      // coalesced per component
        const int p1 = tid + (2 * k + 1) * BLOCK;
        px[k] = f32x2{X[p0], X[p1]};
        py[k] = f32x2{Y[p0], Y[p1]};
        pz[k] = f32x2{Z[p0], Z[p1]};
        dd[k] = f32x2{1e10f, 1e10f};               // BIG
    }
    // Pin the point cloud in VGPRs: opaque identity the allocator can't
    // rematerialize through. (dd is mutable, it stays live on its own.)
#pragma unroll
    for (int k = 0; k < KP2; ++k)
        asm("" : "+v"(px[k]), "+v"(py[k]), "+v"(pz[k]));

    __shared__ unsigned long long s_key[2][NWAVE];  // double-buffered

    const int wave = tid >> 6;
    const int lane = tid & 63;

    // ---- initial far: argmax over x (first occurrence: ascending, strict >)
    int far;
    {
        float bv = px[0].x;
        int   bk = 0;
#pragma unroll
        for (int k = 0; k < KP2; ++k) {
            if (px[k].x > bv) { bv = px[k].x; bk = 2 * k; }
            if (px[k].y > bv) { bv = px[k].y; bk = 2 * k + 1; }
        }
        unsigned long long key = pack_key(bv, tid + bk * BLOCK);
#pragma unroll
        for (int off = 32; off > 0; off >>= 1)
            key = umax64(key, __shfl_xor(key, off));
        if (lane == 0) s_key[0][wave] = key;
        __syncthreads();
        const unsigned long long* sk = s_key[0];
        const unsigned long long bkk =
            umax64(umax64(umax64(sk[0], sk[1]), umax64(sk[2], sk[3])),
                   umax64(umax64(sk[4], sk[5]), umax64(sk[6], sk[7])));
        far = __builtin_amdgcn_readfirstlane(key_idx(bkk));
    }

    // ---- main FPS loop: one barrier per iteration ----
    for (int it = 0; it < NPOINT; ++it) {
        if (tid == 0) cent[b * NPOINT + it] = far;   // record PRE-update far
        if (it == NPOINT - 1) break;                 // last update is unused

        // centroid coords: far is uniform (SGPR) -> scalar broadcast loads
        const float cx = X[far];
        const float cy = Y[far];
        const float cz = Z[far];
        const f32x2 ncx = {-cx, -cx};                // exact negation
        const f32x2 ncy = {-cy, -cy};
        const f32x2 ncz = {-cz, -cz};

        float nbv = -1.0f;
        int   nbk = 0;                               // local k in [0,32)
#pragma unroll
        for (int k = 0; k < KP2; ++k) {
            const f32x2 dx = pk_add(px[k], ncx);     // == px - cx, RN
            const f32x2 dy = pk_add(py[k], ncy);
            const f32x2 dz = pk_add(pz[k], ncz);
            const f32x2 d  = pk_add(pk_add(pk_mul(dx, dx), pk_mul(dy, dy)),
                                    pk_mul(dz, dz));
            const float n0 = fminf(dd[k].x, d.x);
            const float n1 = fminf(dd[k].y, d.y);
            dd[k].x = n0;
            dd[k].y = n1;
            if (n0 > nbv) { nbv = n0; nbk = 2 * k; }      // inline-const idx
            if (n1 > nbv) { nbv = n1; nbk = 2 * k + 1; }
        }

        unsigned long long key = pack_key(nbv, tid + nbk * BLOCK);
#pragma unroll
        for (int off = 32; off > 0; off >>= 1)
            key = umax64(key, __shfl_xor(key, off));
        const int buf = (it + 1) & 1;
        if (lane == 0) s_key[buf][wave] = key;
        __syncthreads();

        const unsigned long long* sk = s_key[buf];
        const unsigned long long bkk =
            umax64(umax64(umax64(sk[0], sk[1]), umax64(sk[2], sk[3])),
                   umax64(umax64(sk[4], sk[5]), umax64(sk[6], sk[7])));
        far = __builtin_amdgcn_readfirstlane(key_idx(bkk));
    }
}

// ---------------------------------------------------------------------------
// Ball query, nsample=1: one wave per centroid; scan 64-point chunks from
// index 0, first hit wins (== min index within radius). Distance replicated
// as the reference einsum: ((-2*dot) + |c|^2) + |p|^2; keep-test d <= 0.25.
// ---------------------------------------------------------------------------
__global__ __launch_bounds__(256) void ballq_kernel(
    const float* __restrict__ xyz,   // [B,3,N]
    const int* __restrict__ cent,    // [B,NPOINT]
    int* __restrict__ out)           // [B,NPOINT]
{
    const int gw   = (blockIdx.x * 256 + threadIdx.x) >> 6; // global wave id
    const int lane = threadIdx.x & 63;
    const int b = gw / NPOINT;
    const int s = gw % NPOINT;

    const float* X = xyz + (size_t)b * 3 * N_PTS;
    const float* Y = X + N_PTS;
    const float* Z = X + 2 * N_PTS;

    const int ci = cent[b * NPOINT + s];
    const float cx = X[ci];
    const float cy = Y[ci];
    const float cz = Z[ci];
    const float cn = __fadd_rn(
        __fadd_rn(__fmul_rn(cx, cx), __fmul_rn(cy, cy)), __fmul_rn(cz, cz));

    int res = N_PTS;
    for (int base = 0; base < N_PTS; base += 64) {
        const int p = base + lane;
        const float x = X[p];
        const float y = Y[p];
        const float z = Z[p];
        const float dot = __fadd_rn(
            __fadd_rn(__fmul_rn(x, cx), __fmul_rn(y, cy)), __fmul_rn(z, cz));
        const float pn = __fadd_rn(
            __fadd_rn(__fmul_rn(x, x), __fmul_rn(y, y)), __fmul_rn(z, z));
        const float d = __fadd_rn(__fadd_rn(__fmul_rn(-2.0f, dot), cn), pn);
        const bool hit = !(d > 0.25f);
        const unsigned long long m = __ballot(hit);
        if (m) {                       // wave-uniform branch
            res = base + (__ffsll((long long)m) - 1);
            break;
        }
    }
    if (lane == 0) out[b * NPOINT + s] = res;
}

extern "C" void kernel_launch(void* const* d_in, const int* in_sizes, int n_in,
                              void* d_out, int out_size, void* d_ws, size_t ws_size,
                              hipStream_t stream) {
    const float* xyz = (const float*)d_in[0];
    const int B = in_sizes[1] / 16;          // cls_label is [B,16]
    int* cent = (int*)d_ws;                  // [B, NPOINT] scratch
    int* out  = (int*)d_out;                 // int32 [B, NPOINT, 1]

    fps_kernel<<<B, BLOCK, 0, stream>>>(xyz, cent);

    const int nwaves  = B * NPOINT;          // one wave per centroid
    const int nblocks = nwaves / 4;          // 256 threads = 4 waves/block
    ballq_kernel<<<nblocks, 256, 0, stream>>>(xyz, cent, out);
}